// Round 2
// 140.539 us; speedup vs baseline: 1.0305x; 1.0305x over previous
//
#include <hip/hip_runtime.h>
#include <math.h>

// R6 (resubmit — round 1 bench died at container level, no kernel verdict).
// Occupancy experiment: 16 lanes/edge, 16 edges/macro-iteration, forced
// __launch_bounds__(256,8) => 64-VGPR cap => 8 waves/SIMD (R5 was 80 VGPR =>
// 4 waves/SIMD, VALUBusy 39%, L2 gather at 16.7 TB/s of ~34 ceiling).
// Register diet vs R5: weights 24->12 (16 lanes/edge), int4 idx blocks 16->0
// (per-lane se/de + ds_swizzle broadcast), accs 24->~15 (incremental pair-tree
// fold), 2-edge ping-pong feature window (16 regs). Cross-iteration se/de
// prefetch breaks the idx->gather serial chain.

typedef _Float16 h2 __attribute__((ext_vector_type(2)));
union U16 { uint4 u; h2 h[4]; };
union HU { uint u; h2 h; };

// ---------- fused conversion kernel: both tables f32 -> f16 ------------------
__global__ __launch_bounds__(256) void cvt_f16_fused_kernel(
    const float4* __restrict__ srcA, int nA4,
    const float4* __restrict__ srcB, int nB4,
    uint2* __restrict__ dst)
{
    int i = blockIdx.x * blockDim.x + threadIdx.x;
    if (i >= nA4 + nB4) return;
    float4 f = (i < nA4) ? srcA[i] : srcB[i - nA4];
    HU a, b;
    a.h = h2{(_Float16)f.x, (_Float16)f.y};
    b.h = h2{(_Float16)f.z, (_Float16)f.w};
    dst[i] = make_uint2(a.u, b.u);
}

// one transpose-reduce stage: lane r accumulates toward edge bit `mask`
__device__ __forceinline__ float foldx(float a, float b, int mask, int r)
{
    const bool hi = (r & mask) != 0;
    const float keep = hi ? b : a;
    const float send = hi ? a : b;
    return keep + __shfl_xor(send, mask, 16);
}

// 12 fdot2 + 4 pk_mul for one edge's 8 elements held by this lane.
__device__ __forceinline__ void dot16(
    const U16& u, const U16& v,
    const h2* __restrict__ wm, const h2* __restrict__ wd, const h2* __restrict__ wp,
    float& m, float& dd, float& pp)
{
#pragma unroll
    for (int jj = 0; jj < 4; ++jj) {
        h2 q = u.h[jj] * v.h[jj];
        m  = __builtin_amdgcn_fdot2(q, wm[jj], m,  false);
        dd = __builtin_amdgcn_fdot2(q, wd[jj], dd, false);
        pp = __builtin_amdgcn_fdot2(q, wp[jj], pp, false);
    }
}

// broadcast lane J's value within each 16-lane group (BitMode swizzle:
// src_lane = (lane & 0x10) | J, compile-time immediate, no addr VALU)
#define SWZB(X, J) __builtin_amdgcn_ds_swizzle((X), 0x10 | ((J) << 5))

// fetch edge J's feature slices for this lane (16 B of u-row, 16 B of v-row)
#define PREF(J, U, V) {                                                   \
    const int su_ = SWZB(se, J);                                          \
    const int sg_ = SWZB(de, J);                                          \
    (U).u = *((const uint4*)(uhalf + (size_t)su_ * 128) + r);             \
    (V).u = *((const uint4*)(ihalf + (size_t)sg_ * 128) + r); }

// ---------- main edge kernel -------------------------------------------------
__global__ __launch_bounds__(256, 8) void zinb_edge16_kernel(
    const _Float16* __restrict__ uhalf,   // [n_cells, 128]
    const _Float16* __restrict__ ihalf,   // [n_genes, 128]
    const float* __restrict__ ge_factor,
    const float* __restrict__ sz_factor,
    const float* __restrict__ W_mean, const float* __restrict__ b_mean,
    const float* __restrict__ W_disp, const float* __restrict__ b_disp,
    const float* __restrict__ W_pi,   const float* __restrict__ b_pi,
    const int* __restrict__ src_idx,
    const int* __restrict__ dst_idx,
    float* __restrict__ out,              // [3E]: mu | disp | pi
    int E)
{
    const int tid = threadIdx.x;
    const int r = tid & 15;
    const int slot = (blockIdx.x * blockDim.x + tid) >> 4;
    const int n_slots = (gridDim.x * blockDim.x) >> 4;
    const int nmac = E >> 4;

    // lane r owns elems [r*8, r*8+8): 12 weight VGPRs total
    h2 wm[4], wd[4], wp[4];
    {
        const float4* a = (const float4*)W_mean + r * 2;
        const float4* b = (const float4*)W_disp + r * 2;
        const float4* c = (const float4*)W_pi   + r * 2;
        float4 a0 = a[0], a1 = a[1];
        float4 b0 = b[0], b1 = b[1];
        float4 c0 = c[0], c1 = c[1];
        wm[0] = h2{(_Float16)a0.x, (_Float16)a0.y}; wm[1] = h2{(_Float16)a0.z, (_Float16)a0.w};
        wm[2] = h2{(_Float16)a1.x, (_Float16)a1.y}; wm[3] = h2{(_Float16)a1.z, (_Float16)a1.w};
        wd[0] = h2{(_Float16)b0.x, (_Float16)b0.y}; wd[1] = h2{(_Float16)b0.z, (_Float16)b0.w};
        wd[2] = h2{(_Float16)b1.x, (_Float16)b1.y}; wd[3] = h2{(_Float16)b1.z, (_Float16)b1.w};
        wp[0] = h2{(_Float16)c0.x, (_Float16)c0.y}; wp[1] = h2{(_Float16)c0.z, (_Float16)c0.w};
        wp[2] = h2{(_Float16)c1.x, (_Float16)c1.y}; wp[3] = h2{(_Float16)c1.z, (_Float16)c1.w};
    }
    const float bm = b_mean[0], bd = b_disp[0], bp = b_pi[0];

    // prologue: per-lane own-edge indices for the first iteration
    int se = 0, de = 0;
    if (slot < nmac) {
        se = src_idx[(slot << 4) + r];
        de = dst_idx[(slot << 4) + r];
    }

    for (int q = slot; q < nmac; q += n_slots) {
        const int e0 = q << 4;
        const float szf = sz_factor[se];   // own-edge factor gathers (L1-hot)
        const float gef = ge_factor[de];

        U16 xu, xv, yu, yv;                // ping-pong: even edges x, odd y
        PREF(0, xu, xv)
        PREF(1, yu, yv)

        // cross-iteration index prefetch (hides idx->gather chain of next q)
        const int qn = q + n_slots;
        const int en0 = ((qn < nmac) ? qn : q) << 4;
        const int se_n = src_idx[en0 + r];
        const int de_n = dst_idx[en0 + r];

        float Hm0, Hd0, Hp0;
        {
            float Am, Ad, Ap;              // edges 0..3
            {
                float m0 = 0.f, d0 = 0.f, p0 = 0.f;
                dot16(xu, xv, wm, wd, wp, m0, d0, p0); PREF(2, xu, xv)
                float m1 = 0.f, d1 = 0.f, p1 = 0.f;
                dot16(yu, yv, wm, wd, wp, m1, d1, p1); PREF(3, yu, yv)
                const float t0m = foldx(m0, m1, 1, r);
                const float t0d = foldx(d0, d1, 1, r);
                const float t0p = foldx(p0, p1, 1, r);
                float m2 = 0.f, d2 = 0.f, p2 = 0.f;
                dot16(xu, xv, wm, wd, wp, m2, d2, p2); PREF(4, xu, xv)
                float m3 = 0.f, d3 = 0.f, p3 = 0.f;
                dot16(yu, yv, wm, wd, wp, m3, d3, p3); PREF(5, yu, yv)
                const float t1m = foldx(m2, m3, 1, r);
                const float t1d = foldx(d2, d3, 1, r);
                const float t1p = foldx(p2, p3, 1, r);
                Am = foldx(t0m, t1m, 2, r);
                Ad = foldx(t0d, t1d, 2, r);
                Ap = foldx(t0p, t1p, 2, r);
            }
            float Bm, Bd, Bp;              // edges 4..7
            {
                float m0 = 0.f, d0 = 0.f, p0 = 0.f;
                dot16(xu, xv, wm, wd, wp, m0, d0, p0); PREF(6, xu, xv)
                float m1 = 0.f, d1 = 0.f, p1 = 0.f;
                dot16(yu, yv, wm, wd, wp, m1, d1, p1); PREF(7, yu, yv)
                const float t0m = foldx(m0, m1, 1, r);
                const float t0d = foldx(d0, d1, 1, r);
                const float t0p = foldx(p0, p1, 1, r);
                float m2 = 0.f, d2 = 0.f, p2 = 0.f;
                dot16(xu, xv, wm, wd, wp, m2, d2, p2); PREF(8, xu, xv)
                float m3 = 0.f, d3 = 0.f, p3 = 0.f;
                dot16(yu, yv, wm, wd, wp, m3, d3, p3); PREF(9, yu, yv)
                const float t1m = foldx(m2, m3, 1, r);
                const float t1d = foldx(d2, d3, 1, r);
                const float t1p = foldx(p2, p3, 1, r);
                Bm = foldx(t0m, t1m, 2, r);
                Bd = foldx(t0d, t1d, 2, r);
                Bp = foldx(t0p, t1p, 2, r);
            }
            Hm0 = foldx(Am, Bm, 4, r);
            Hd0 = foldx(Ad, Bd, 4, r);
            Hp0 = foldx(Ap, Bp, 4, r);
        }
        float Hm1, Hd1, Hp1;
        {
            float Cm, Cd, Cp;              // edges 8..11
            {
                float m0 = 0.f, d0 = 0.f, p0 = 0.f;
                dot16(xu, xv, wm, wd, wp, m0, d0, p0); PREF(10, xu, xv)
                float m1 = 0.f, d1 = 0.f, p1 = 0.f;
                dot16(yu, yv, wm, wd, wp, m1, d1, p1); PREF(11, yu, yv)
                const float t0m = foldx(m0, m1, 1, r);
                const float t0d = foldx(d0, d1, 1, r);
                const float t0p = foldx(p0, p1, 1, r);
                float m2 = 0.f, d2 = 0.f, p2 = 0.f;
                dot16(xu, xv, wm, wd, wp, m2, d2, p2); PREF(12, xu, xv)
                float m3 = 0.f, d3 = 0.f, p3 = 0.f;
                dot16(yu, yv, wm, wd, wp, m3, d3, p3); PREF(13, yu, yv)
                const float t1m = foldx(m2, m3, 1, r);
                const float t1d = foldx(d2, d3, 1, r);
                const float t1p = foldx(p2, p3, 1, r);
                Cm = foldx(t0m, t1m, 2, r);
                Cd = foldx(t0d, t1d, 2, r);
                Cp = foldx(t0p, t1p, 2, r);
            }
            float Dm, Dd, Dp;              // edges 12..15
            {
                float m0 = 0.f, d0 = 0.f, p0 = 0.f;
                dot16(xu, xv, wm, wd, wp, m0, d0, p0); PREF(14, xu, xv)
                float m1 = 0.f, d1 = 0.f, p1 = 0.f;
                dot16(yu, yv, wm, wd, wp, m1, d1, p1); PREF(15, yu, yv)
                const float t0m = foldx(m0, m1, 1, r);
                const float t0d = foldx(d0, d1, 1, r);
                const float t0p = foldx(p0, p1, 1, r);
                float m2 = 0.f, d2 = 0.f, p2 = 0.f;
                dot16(xu, xv, wm, wd, wp, m2, d2, p2);
                float m3 = 0.f, d3 = 0.f, p3 = 0.f;
                dot16(yu, yv, wm, wd, wp, m3, d3, p3);
                const float t1m = foldx(m2, m3, 1, r);
                const float t1d = foldx(d2, d3, 1, r);
                const float t1p = foldx(p2, p3, 1, r);
                Dm = foldx(t0m, t1m, 2, r);
                Dd = foldx(t0d, t1d, 2, r);
                Dp = foldx(t0p, t1p, 2, r);
            }
            Hm1 = foldx(Cm, Dm, 4, r);
            Hd1 = foldx(Cd, Dd, 4, r);
            Hp1 = foldx(Cp, Dp, 4, r);
        }
        const float Fm = foldx(Hm0, Hm1, 8, r);
        const float Fd = foldx(Hd0, Hd1, 8, r);
        const float Fp = foldx(Hp0, Hp1, 8, r);

        // full-wave epilogue (lane r = edge e0 + r)
        const float mu_ = 1.f / (1.f + __expf(-(Fm + bm)));
        const float pi  = 1.f / (1.f + __expf(-(Fp + bp)));
        const float xd  = gef * (Fd + bd);
        const float sp  = fmaxf(xd, 0.f) + __logf(1.f + __expf(-fabsf(xd)));
        const float disp = fminf(fmaxf(sp, 1e-4f), 1e4f);
        const float mu = szf * fminf(fmaxf(__expf(gef * mu_) - 1.f, 1e-5f), 1e6f);

        const int e = e0 + r;
        out[e]                 = mu;
        out[(size_t)E + e]     = disp;
        out[(size_t)2 * E + e] = pi;

        se = se_n; de = de_n;
    }
}

// ---------- tail kernel: last E%16 edges, scalar f32 -------------------------
__global__ void zinb_tail_kernel(
    const float* __restrict__ ufeats, const float* __restrict__ ifeats,
    const float* __restrict__ ge_factor, const float* __restrict__ sz_factor,
    const float* __restrict__ W_mean, const float* __restrict__ b_mean,
    const float* __restrict__ W_disp, const float* __restrict__ b_disp,
    const float* __restrict__ W_pi,   const float* __restrict__ b_pi,
    const int* __restrict__ src_idx, const int* __restrict__ dst_idx,
    float* __restrict__ out, int E, int start)
{
    int e = start + blockIdx.x * blockDim.x + threadIdx.x;
    if (e >= E) return;
    const int s = src_idx[e], g = dst_idx[e];
    float am = 0.f, ad = 0.f, ap = 0.f;
    for (int k = 0; k < 128; ++k) {
        float h = ufeats[(size_t)s * 128 + k] * ifeats[(size_t)g * 128 + k];
        am = fmaf(h, W_mean[k], am);
        ad = fmaf(h, W_disp[k], ad);
        ap = fmaf(h, W_pi[k],   ap);
    }
    const float gef = ge_factor[g];
    const float szf = sz_factor[s];
    const float mu_ = 1.f / (1.f + __expf(-(am + b_mean[0])));
    const float pi  = 1.f / (1.f + __expf(-(ap + b_pi[0])));
    const float xd  = gef * (ad + b_disp[0]);
    const float sp  = fmaxf(xd, 0.f) + __logf(1.f + __expf(-fabsf(xd)));
    const float disp = fminf(fmaxf(sp, 1e-4f), 1e4f);
    const float mu = szf * fminf(fmaxf(__expf(gef * mu_) - 1.f, 1e-5f), 1e6f);
    out[e] = mu; out[(size_t)E + e] = disp; out[(size_t)2 * E + e] = pi;
}

// ---------- fallback: pure-f32 kernel (ws too small) -------------------------
__global__ __launch_bounds__(256) void zinb_edge_f32_kernel(
    const float* __restrict__ ufeats, const float* __restrict__ ifeats,
    const float* __restrict__ ge_factor, const float* __restrict__ sz_factor,
    const float* __restrict__ W_mean, const float* __restrict__ b_mean,
    const float* __restrict__ W_disp, const float* __restrict__ b_disp,
    const float* __restrict__ W_pi,   const float* __restrict__ b_pi,
    const int* __restrict__ src_idx, const int* __restrict__ dst_idx,
    float* __restrict__ out, int E)
{
    const int r = threadIdx.x & 7;
    const int slot = (blockIdx.x * blockDim.x + threadIdx.x) >> 3;
    const int n_slots = (gridDim.x * blockDim.x) >> 3;

    float4 wm[4], wd[4], wp[4];
    {
        const float4* wm4 = (const float4*)W_mean + r;
        const float4* wd4 = (const float4*)W_disp + r;
        const float4* wp4 = (const float4*)W_pi   + r;
#pragma unroll
        for (int c = 0; c < 4; ++c) { wm[c] = wm4[c*8]; wd[c] = wd4[c*8]; wp[c] = wp4[c*8]; }
    }
    const float bm = b_mean[0], bd = b_disp[0], bp = b_pi[0];

    for (int e = slot; e < E; e += n_slots) {
        const int s = src_idx[e];
        const int g = dst_idx[e];
        const float4* u4 = (const float4*)(ufeats + (size_t)s * 128) + r;
        const float4* v4 = (const float4*)(ifeats + (size_t)g * 128) + r;
        float am = 0.f, ad = 0.f, ap = 0.f;
#pragma unroll
        for (int c = 0; c < 4; ++c) {
            float4 u = u4[c*8]; float4 v = v4[c*8];
            float px = u.x*v.x, py = u.y*v.y, pz = u.z*v.z, pw = u.w*v.w;
            am = fmaf(px, wm[c].x, am); am = fmaf(py, wm[c].y, am);
            am = fmaf(pz, wm[c].z, am); am = fmaf(pw, wm[c].w, am);
            ad = fmaf(px, wd[c].x, ad); ad = fmaf(py, wd[c].y, ad);
            ad = fmaf(pz, wd[c].z, ad); ad = fmaf(pw, wd[c].w, ad);
            ap = fmaf(px, wp[c].x, ap); ap = fmaf(py, wp[c].y, ap);
            ap = fmaf(pz, wp[c].z, ap); ap = fmaf(pw, wp[c].w, ap);
        }
#pragma unroll
        for (int off = 1; off < 8; off <<= 1) {
            am += __shfl_xor(am, off); ad += __shfl_xor(ad, off); ap += __shfl_xor(ap, off);
        }
        if (r == 0) {
            const float gef = ge_factor[g];
            const float szf = sz_factor[s];
            const float mu_ = 1.f / (1.f + __expf(-(am + bm)));
            const float pi  = 1.f / (1.f + __expf(-(ap + bp)));
            const float xd  = gef * (ad + bd);
            const float sp  = fmaxf(xd, 0.f) + __logf(1.f + __expf(-fabsf(xd)));
            const float disp = fminf(fmaxf(sp, 1e-4f), 1e4f);
            const float mu = szf * fminf(fmaxf(__expf(gef * mu_) - 1.f, 1e-5f), 1e6f);
            out[e] = mu; out[(size_t)E + e] = disp; out[(size_t)2*E + e] = pi;
        }
    }
}

extern "C" void kernel_launch(void* const* d_in, const int* in_sizes, int n_in,
                              void* d_out, int out_size, void* d_ws, size_t ws_size,
                              hipStream_t stream) {
    const float* ufeats    = (const float*)d_in[0];
    const float* ifeats    = (const float*)d_in[1];
    const float* ge_factor = (const float*)d_in[2];
    const float* sz_factor = (const float*)d_in[3];
    const float* W_mean    = (const float*)d_in[4];
    const float* b_mean    = (const float*)d_in[5];
    const float* W_disp    = (const float*)d_in[6];
    const float* b_disp    = (const float*)d_in[7];
    const float* W_pi      = (const float*)d_in[8];
    const float* b_pi      = (const float*)d_in[9];
    const int*   src_idx   = (const int*)d_in[10];
    const int*   dst_idx   = (const int*)d_in[11];
    float* out = (float*)d_out;

    const int E       = in_sizes[10];
    const int n_cells = in_sizes[0] / 128;
    const int n_genes = in_sizes[1] / 128;

    const size_t u_elems = (size_t)n_cells * 128;
    const size_t i_elems = (size_t)n_genes * 128;
    const size_t ws_needed = (u_elems + i_elems) * sizeof(_Float16);

    if (ws_size >= ws_needed) {
        _Float16* uhalf = (_Float16*)d_ws;
        _Float16* ihalf = uhalf + u_elems;

        const int un4 = (int)(u_elems / 4);
        const int in4 = (int)(i_elems / 4);
        const int n4  = un4 + in4;
        hipLaunchKernelGGL(cvt_f16_fused_kernel, dim3((n4 + 255) / 256), dim3(256), 0, stream,
                           (const float4*)ufeats, un4, (const float4*)ifeats, in4,
                           (uint2*)d_ws);

        hipLaunchKernelGGL(zinb_edge16_kernel, dim3(2048), dim3(256), 0, stream,
                           uhalf, ihalf, ge_factor, sz_factor,
                           W_mean, b_mean, W_disp, b_disp, W_pi, b_pi,
                           src_idx, dst_idx, out, E);

        const int rem = E & 15;
        if (rem) {
            hipLaunchKernelGGL(zinb_tail_kernel, dim3(1), dim3(64), 0, stream,
                               ufeats, ifeats, ge_factor, sz_factor,
                               W_mean, b_mean, W_disp, b_disp, W_pi, b_pi,
                               src_idx, dst_idx, out, E, E - rem);
        }
    } else {
        hipLaunchKernelGGL(zinb_edge_f32_kernel, dim3(2048), dim3(256), 0, stream,
                           ufeats, ifeats, ge_factor, sz_factor,
                           W_mean, b_mean, W_disp, b_disp, W_pi, b_pi,
                           src_idx, dst_idx, out, E);
    }
}